// Round 9
// baseline (201.386 us; speedup 1.0000x reference)
//
#include <hip/hip_runtime.h>

#define EPSF 1e-8f

constexpr int D0 = 128;   // input dim
constexpr int R  = 256;   // random features
constexpr int D1 = 64;    // output dim
constexpr int BM = 32;    // rows per block
constexpr int NT = 256;   // threads per block (4 waves)
constexpr int TP = 68;    // transpose buffer stride (f32): 16B-aligned rows

typedef __attribute__((ext_vector_type(8))) short  bf16x8;
typedef __attribute__((ext_vector_type(4))) float  f32x4;
typedef __attribute__((ext_vector_type(4))) uint   u32x4;

// ws layout (ushort elements): bf16 weights in MFMA fragment order
//   [0]      w1mu  frags (64 frags)
//   [32768]  w1var frags
//   [65536]  w2mu  frags (32 frags)          -> m2
//   [81920]  w2c   frags (= w2var + w2mu^2)  -> v2, multiplies v1
//   [98304]  w2var frags                     -> v2, multiplies m1^2
constexpr int WS_W1VAR = 32768;
constexpr int WS_W2MU  = 65536;
constexpr int WS_W2C   = 81920;
constexpr int WS_W2VAR = 98304;

__device__ __forceinline__ ushort f2bf(float x) {
    uint32_t u = __builtin_bit_cast(uint32_t, x);
    u += 0x7FFFu + ((u >> 16) & 1u);          // round-to-nearest-even
    return (ushort)(u >> 16);
}

// packed f32x2 -> bf16x2 (RNE), 1 VALU inst
__device__ __forceinline__ uint cvt_pk_bf16(float lo, float hi) {
    uint r;
    asm("v_cvt_pk_bf16_f32 %0, %1, %2" : "=v"(r) : "v"(lo), "v"(hi));
    return r;
}

// elementwise square of a bf16x8 fragment (bf16->f32 is a shift)
__device__ __forceinline__ bf16x8 sq_bf16x8(bf16x8 a) {
    u32x4 u = __builtin_bit_cast(u32x4, a);
    u32x4 r;
    #pragma unroll
    for (int i = 0; i < 4; ++i) {
        float lo = __builtin_bit_cast(float, u[i] << 16);
        float hi = __builtin_bit_cast(float, u[i] & 0xFFFF0000u);
        r[i] = cvt_pk_bf16(lo * lo, hi * hi);
    }
    return __builtin_bit_cast(bf16x8, r);
}

// --- pre-kernel: convert weights to bf16 in MFMA fragment order ------------
__global__ void convert_w(const float* __restrict__ W1mu,
                          const float* __restrict__ W1var,
                          const float* __restrict__ W2mu,
                          const float* __restrict__ W2var,
                          ushort* __restrict__ ws)
{
    int tid = blockIdx.x * 256 + threadIdx.x;
    if (tid < 8192) {                       // layer 1: 2 mats * 64 frags * 64 lanes
        int m    = tid >> 12;               // 0=mu 1=var
        int f    = (tid >> 6) & 63;         // frag = nt*4 + ks
        int lane = tid & 63;
        int nt = f >> 2, ks = f & 3;
        int col = nt * 16 + (lane & 15);    // rf index (W1 row)
        int k0  = ks * 32 + (lane >> 4) * 8;
        const float* src = (m ? W1var : W1mu) + (size_t)col * D0 + k0;
        ushort* dst = ws + (m ? WS_W1VAR : 0) + (size_t)(f * 64 + lane) * 8;
        #pragma unroll
        for (int j = 0; j < 8; ++j) dst[j] = f2bf(src[j]);
    } else if (tid < 8192 + 3 * 2048) {     // layer 2: 3 mats * 32 frags * 64 lanes
        int t2   = tid - 8192;
        int m    = t2 >> 11;                // 0=mu 1=c 2=var
        int f    = (t2 >> 6) & 31;          // frag = nt*8 + ks
        int lane = t2 & 63;
        int nt = f >> 3, ks = f & 7;
        int col = nt * 16 + (lane & 15);    // d1 index (W2 row)
        int k0  = ks * 32 + (lane >> 4) * 8;
        const float* smu = W2mu  + (size_t)col * R + k0;
        const float* svr = W2var + (size_t)col * R + k0;
        ushort* dst = ws + WS_W2MU + m * 16384 + (size_t)(f * 64 + lane) * 8;
        #pragma unroll
        for (int j = 0; j < 8; ++j) {
            float v;
            if (m == 0)      v = smu[j];
            else if (m == 1) v = fmaf(smu[j], smu[j], svr[j]);  // var + mu^2
            else             v = svr[j];
            dst[j] = f2bf(v);
        }
    }
}

// --- fused main kernel ------------------------------------------------------
// Operand-swapped GEMMs (D = W·X^T). 32 KB LDS.
// Layer-2 work split: wave w -> rows (w>>1)*16..+16, d1 (w&1)*32..+32 so each
// wave reads HALF the slab (16 b128 vs 32) — LDS pipe is the shared binder.
__global__ __launch_bounds__(NT, 4)
void dgp_mfma(const float* __restrict__ X,
              const int*   __restrict__ Xidx,
              const ushort* __restrict__ ws,
              float* __restrict__ accM,
              float* __restrict__ accP)
{
    __shared__ __align__(16) ushort sh[2 * BM * R];
    ushort* M1s = sh;
    ushort* V1s = sh + BM * R;

    const int t    = threadIdx.x;
    const int lane = t & 63;
    const int w    = t >> 6;         // wave 0..3
    const int row0 = blockIdx.x * BM;
    const int lcol = lane & 15;      // X-row within 16-tile
    const int lk   = lane >> 4;      // 0..3

    // ---------------- Layer 1: W1·X^T (mu) and W1var·(X^2)^T ----------------
    f32x4 accm[2][4], accv[2][4];   // [rt][nt]
    #pragma unroll
    for (int rt = 0; rt < 2; ++rt)
        #pragma unroll
        for (int nt = 0; nt < 4; ++nt) {
            accm[rt][nt] = (f32x4)0.f;
            accv[rt][nt] = (f32x4)0.f;
        }

    #pragma unroll
    for (int ks = 0; ks < 4; ++ks) {
        bf16x8 xb[2], xq[2];
        #pragma unroll
        for (int rt = 0; rt < 2; ++rt) {
            const float* xp = X + (size_t)(row0 + rt * 16 + lcol) * D0 + ks * 32 + lk * 8;
            float4 a = *(const float4*)xp;
            float4 b = *(const float4*)(xp + 4);
            u32x4 um, uq;
            um[0] = cvt_pk_bf16(a.x, a.y);
            um[1] = cvt_pk_bf16(a.z, a.w);
            um[2] = cvt_pk_bf16(b.x, b.y);
            um[3] = cvt_pk_bf16(b.z, b.w);
            uq[0] = cvt_pk_bf16(a.x * a.x, a.y * a.y);
            uq[1] = cvt_pk_bf16(a.z * a.z, a.w * a.w);
            uq[2] = cvt_pk_bf16(b.x * b.x, b.y * b.y);
            uq[3] = cvt_pk_bf16(b.z * b.z, b.w * b.w);
            xb[rt] = __builtin_bit_cast(bf16x8, um);
            xq[rt] = __builtin_bit_cast(bf16x8, uq);
        }
        #pragma unroll
        for (int nt = 0; nt < 4; ++nt) {
            int f = (w * 4 + nt) * 4 + ks;
            bf16x8 amu = *(const bf16x8*)(ws + (size_t)(f * 64 + lane) * 8);
            bf16x8 avr = *(const bf16x8*)(ws + WS_W1VAR + (size_t)(f * 64 + lane) * 8);
            #pragma unroll
            for (int rt = 0; rt < 2; ++rt) {
                accm[rt][nt] = __builtin_amdgcn_mfma_f32_16x16x32_bf16(amu, xb[rt], accm[rt][nt], 0, 0, 0);
                accv[rt][nt] = __builtin_amdgcn_mfma_f32_16x16x32_bf16(avr, xq[rt], accv[rt][nt], 0, 0, 0);
            }
        }
    }

    // RF-ReLU epilogue -> b64 LDS writes (XOR-swizzled, 16B granule)
    const float SCALE  = 0.08838834764831845f;  // sqrt(2/256)
    const float SCALE2 = 0.0078125f;            // 2/256
    #pragma unroll
    for (int rt = 0; rt < 2; ++rt) {
        int xrow = rt * 16 + lcol;
        int swz  = (xrow & 7) << 3;
        int rowb = xrow * 256;
        #pragma unroll
        for (int nt = 0; nt < 4; ++nt) {
            int rf0 = (w * 4 + nt) * 16 + lk * 4;
            float m1[4], v1[4];
            #pragma unroll
            for (int i = 0; i < 4; ++i) {
                float om = accm[rt][nt][i];
                float ov = accv[rt][nt][i];
                bool pos = om > 0.f;
                m1[i] = pos ? SCALE  * om : 0.f;
                v1[i] = pos ? SCALE2 * ov : 0.f;
            }
            uint2 pm, pv;
            pm.x = cvt_pk_bf16(m1[0], m1[1]); pm.y = cvt_pk_bf16(m1[2], m1[3]);
            pv.x = cvt_pk_bf16(v1[0], v1[1]); pv.y = cvt_pk_bf16(v1[2], v1[3]);
            int idx = rowb + (rf0 ^ swz);
            *(uint2*)&M1s[idx] = pm;
            *(uint2*)&V1s[idx] = pv;
        }
    }

    __syncthreads();

    // ---------------- Layer 2: W2·slab^T moment GEMMs (K=256) ---------------
    // wave w: rows rt2*16..+16 (rt2 = w>>1), d1 = ntp*32 .. +32 (ntp = w&1)
    const int rt2 = w >> 1;
    const int ntp = w & 1;
    const int xrow2 = rt2 * 16 + lcol;
    const int swz2  = (xrow2 & 7) << 3;
    const int rowb2 = xrow2 * 256;

    f32x4 m2a[2], v2a[2];   // [ntl]
    #pragma unroll
    for (int ntl = 0; ntl < 2; ++ntl) { m2a[ntl] = (f32x4)0.f; v2a[ntl] = (f32x4)0.f; }

    #pragma unroll
    for (int ks = 0; ks < 8; ++ks) {
        int base = rowb2 + ((ks * 32 + lk * 8) ^ swz2);
        bf16x8 bm  = *(const bf16x8*)&M1s[base];
        bf16x8 bv  = *(const bf16x8*)&V1s[base];
        bf16x8 bms = sq_bf16x8(bm);        // once per ks, reused by both ntl
        #pragma unroll
        for (int ntl = 0; ntl < 2; ++ntl) {
            int f = (ntp * 2 + ntl) * 8 + ks;
            bf16x8 amu = *(const bf16x8*)(ws + WS_W2MU  + (size_t)(f * 64 + lane) * 8);
            bf16x8 ac  = *(const bf16x8*)(ws + WS_W2C   + (size_t)(f * 64 + lane) * 8);
            bf16x8 avr = *(const bf16x8*)(ws + WS_W2VAR + (size_t)(f * 64 + lane) * 8);
            m2a[ntl] = __builtin_amdgcn_mfma_f32_16x16x32_bf16(amu, bm,  m2a[ntl], 0, 0, 0);
            v2a[ntl] = __builtin_amdgcn_mfma_f32_16x16x32_bf16(ac,  bv,  v2a[ntl], 0, 0, 0);
            v2a[ntl] = __builtin_amdgcn_mfma_f32_16x16x32_bf16(avr, bms, v2a[ntl], 0, 0, 0);
        }
    }

    __syncthreads();   // all layer-2 LDS reads done before slab reuse

    // ---------------- Transpose (p, p*m) through LDS ------------------------
    // [32][68] f32: 16B-aligned rows -> b128 writes; Pl+Ml = 17.4 KB aliased
    float* Pl = (float*)sh;            // [32][TP]
    float* Ml = Pl + BM * TP;          // [32][TP]
    #pragma unroll
    for (int ntl = 0; ntl < 2; ++ntl) {
        int d1 = ntp * 32 + ntl * 16 + lk * 4;
        f32x4 pv, mv;
        #pragma unroll
        for (int i = 0; i < 4; ++i) {
            float p = 1.0f / (v2a[ntl][i] + EPSF);
            pv[i] = p;
            mv[i] = p * m2a[ntl][i];
        }
        *(f32x4*)&Pl[xrow2 * TP + d1] = pv;
        *(f32x4*)&Ml[xrow2 * TP + d1] = mv;
    }

    __syncthreads();

    // ---------------- Row-coalesced atomic scatter --------------------------
    // wave w handles rows w*8 .. w*8+7; per instruction: one uniform row,
    // 64 lanes = 64 consecutive floats = 256B dense region
    #pragma unroll
    for (int r = 0; r < 8; ++r) {
        int row = w * 8 + r;
        int g   = __builtin_amdgcn_readfirstlane(Xidx[row0 + row]);
        float pv = Pl[row * TP + lane];
        float mv = Ml[row * TP + lane];
        atomicAdd(accP + (size_t)g * D1 + lane, pv);
        atomicAdd(accM + (size_t)g * D1 + lane, mv);
    }
}

__global__ void dgp_finalize(float* __restrict__ accM,
                             float* __restrict__ accP, int total)
{
    int idx = blockIdx.x * blockDim.x + threadIdx.x;
    if (idx < total) {
        float var = 1.0f / (accP[idx] + EPSF);   // p_sum = seg_sum + EPS
        accP[idx] = var;                         // embedd_vars
        accM[idx] = accM[idx] * var;             // embedd_means
    }
}

extern "C" void kernel_launch(void* const* d_in, const int* in_sizes, int n_in,
                              void* d_out, int out_size, void* d_ws, size_t ws_size,
                              hipStream_t stream)
{
    const float* X     = (const float*)d_in[0];
    const int*   Xidx  = (const int*)d_in[1];
    const float* W1mu  = (const float*)d_in[2];
    const float* W1var = (const float*)d_in[3];
    const float* W2mu  = (const float*)d_in[4];
    const float* W2var = (const float*)d_in[5];

    const int N = in_sizes[0] / D0;            // 262144
    const int U = out_size / (2 * D1);         // 50000
    float* out  = (float*)d_out;
    float* accM = out;                          // means region
    float* accP = out + (size_t)U * D1;         // vars region
    ushort* ws  = (ushort*)d_ws;

    // harness does not re-poison between replays: re-zero accumulators
    hipMemsetAsync(d_out, 0, (size_t)out_size * sizeof(float), stream);

    convert_w<<<56, 256, 0, stream>>>(W1mu, W1var, W2mu, W2var, ws);

    dgp_mfma<<<N / BM, NT, 0, stream>>>(X, Xidx, ws, accM, accP);

    const int total = U * D1;
    dgp_finalize<<<(total + 255) / 256, 256, 0, stream>>>(accM, accP, total);
}

// Round 10
// 169.475 us; speedup vs baseline: 1.1883x; 1.1883x over previous
//
#include <hip/hip_runtime.h>

#define EPSF 1e-8f

constexpr int D0 = 128;   // input dim
constexpr int R  = 256;   // random features
constexpr int D1 = 64;    // output dim
constexpr int BM = 64;    // rows per block
constexpr int NT = 512;   // threads per block (8 waves)
constexpr int TP = 68;    // transpose buffer stride (f32)

typedef __attribute__((ext_vector_type(8))) short  bf16x8;
typedef __attribute__((ext_vector_type(4))) float  f32x4;
typedef __attribute__((ext_vector_type(4))) uint   u32x4;

// ws layout (ushort elements): bf16 weights in MFMA fragment order
constexpr int WS_W1VAR = 32768;
constexpr int WS_W2MU  = 65536;
constexpr int WS_W2C   = 81920;
constexpr int WS_W2VAR = 98304;

__device__ __forceinline__ ushort f2bf(float x) {
    uint32_t u = __builtin_bit_cast(uint32_t, x);
    u += 0x7FFFu + ((u >> 16) & 1u);          // round-to-nearest-even
    return (ushort)(u >> 16);
}

__device__ __forceinline__ uint cvt_pk_bf16(float lo, float hi) {
    uint r;
    asm("v_cvt_pk_bf16_f32 %0, %1, %2" : "=v"(r) : "v"(lo), "v"(hi));
    return r;
}

// elementwise square of a bf16x8 fragment
__device__ __forceinline__ bf16x8 sq_bf16x8(bf16x8 a) {
    u32x4 u = __builtin_bit_cast(u32x4, a);
    u32x4 r;
    #pragma unroll
    for (int i = 0; i < 4; ++i) {
        float lo = __builtin_bit_cast(float, u[i] << 16);
        float hi = __builtin_bit_cast(float, u[i] & 0xFFFF0000u);
        r[i] = cvt_pk_bf16(lo * lo, hi * hi);
    }
    return __builtin_bit_cast(bf16x8, r);
}

// --- pre-kernel: convert weights to bf16 in MFMA fragment order ------------
__global__ void convert_w(const float* __restrict__ W1mu,
                          const float* __restrict__ W1var,
                          const float* __restrict__ W2mu,
                          const float* __restrict__ W2var,
                          ushort* __restrict__ ws)
{
    int tid = blockIdx.x * 256 + threadIdx.x;
    if (tid < 8192) {                       // layer 1: 2 mats * 64 frags * 64 lanes
        int m    = tid >> 12;               // 0=mu 1=var
        int f    = (tid >> 6) & 63;         // frag = nt*4 + ks
        int lane = tid & 63;
        int nt = f >> 2, ks = f & 3;
        int col = nt * 16 + (lane & 15);    // rf index (W1 row)
        int k0  = ks * 32 + (lane >> 4) * 8;
        const float* src = (m ? W1var : W1mu) + (size_t)col * D0 + k0;
        ushort* dst = ws + (m ? WS_W1VAR : 0) + (size_t)(f * 64 + lane) * 8;
        #pragma unroll
        for (int j = 0; j < 8; ++j) dst[j] = f2bf(src[j]);
    } else if (tid < 8192 + 3 * 2048) {     // layer 2: 3 mats * 32 frags * 64 lanes
        int t2   = tid - 8192;
        int m    = t2 >> 11;                // 0=mu 1=c 2=var
        int f    = (t2 >> 6) & 31;          // frag = nt*8 + ks
        int lane = t2 & 63;
        int nt = f >> 3, ks = f & 7;
        int col = nt * 16 + (lane & 15);    // d1 index (W2 row)
        int k0  = ks * 32 + (lane >> 4) * 8;
        const float* smu = W2mu  + (size_t)col * R + k0;
        const float* svr = W2var + (size_t)col * R + k0;
        ushort* dst = ws + WS_W2MU + m * 16384 + (size_t)(f * 64 + lane) * 8;
        #pragma unroll
        for (int j = 0; j < 8; ++j) {
            float v;
            if (m == 0)      v = smu[j];
            else if (m == 1) v = fmaf(smu[j], smu[j], svr[j]);  // var + mu^2
            else             v = svr[j];
            dst[j] = f2bf(v);
        }
    }
}

// --- fused main kernel ------------------------------------------------------
// BM=64, 8 waves. Goal: halve L2 traffic (the ~200us invariant binder).
//  - X staged once into LDS (granule-XOR swizzle), read as MFMA B-frags
//  - layer 1: wave owns 2 rf-tiles x all 4 row-tiles (disjoint weight frags)
//  - layer 2: wave = (d1-tile, ks-half) -> disjoint weight frags; partial
//    (m2,v2) combined through the LDS transpose buffer
__global__ __launch_bounds__(NT, 4)
void dgp_mfma(const float* __restrict__ X,
              const int*   __restrict__ Xidx,
              const ushort* __restrict__ ws,
              float* __restrict__ accM,
              float* __restrict__ accP)
{
    // 64 KB, phase-aliased:
    //  A: float Xs[64][128]            (32 KB, granule-XOR swizzle)
    //  B: ushort M1s/V1s[64][256]      (32+32 KB, XOR swizzle)
    //  C: float Vp/Mp[64][68]          (17.4+17.4 KB)
    __shared__ __align__(16) ushort sh[2 * BM * R];
    ushort* M1s = sh;
    ushort* V1s = sh + BM * R;

    const int t    = threadIdx.x;
    const int lane = t & 63;
    const int w    = t >> 6;         // wave 0..7
    const int row0 = blockIdx.x * BM;
    const int lcol = lane & 15;      // X-row within 16-tile
    const int lk   = lane >> 4;      // 0..3

    // ---------------- Stage X into LDS (once, coalesced) --------------------
    {
        float* Xs = (float*)sh;
        const float4* X4 = (const float4*)(X + (size_t)row0 * D0);
        #pragma unroll
        for (int i = 0; i < 4; ++i) {
            int g   = t + NT * i;          // 0..2047 float4s (64 rows x 32)
            int row = g >> 5, c4 = g & 31;
            float4 v = X4[g];
            int gran = c4 ^ (row & 7);     // 16B-granule XOR swizzle
            *(float4*)&Xs[row * 128 + gran * 4] = v;
        }
    }
    __syncthreads();

    // ---------------- Layer 1: W1·X^T (mu) and W1var·(X^2)^T ----------------
    // wave w owns rf-tiles {2w, 2w+1}, all 4 row-tiles
    const float* Xs = (const float*)sh;
    f32x4 accm[2][4], accv[2][4];   // [ntl][rt]
    #pragma unroll
    for (int ntl = 0; ntl < 2; ++ntl)
        #pragma unroll
        for (int rt = 0; rt < 4; ++rt) {
            accm[ntl][rt] = (f32x4)0.f;
            accv[ntl][rt] = (f32x4)0.f;
        }

    #pragma unroll
    for (int ks = 0; ks < 4; ++ks) {
        bf16x8 amu[2], avr[2];
        #pragma unroll
        for (int ntl = 0; ntl < 2; ++ntl) {
            int f = (w * 2 + ntl) * 4 + ks;
            amu[ntl] = *(const bf16x8*)(ws + (size_t)(f * 64 + lane) * 8);
            avr[ntl] = *(const bf16x8*)(ws + WS_W1VAR + (size_t)(f * 64 + lane) * 8);
        }
        #pragma unroll
        for (int rt = 0; rt < 4; ++rt) {
            int xrow = rt * 16 + lcol;
            int g0 = (ks * 8 + lk * 2) ^ (xrow & 7);
            int g1 = (ks * 8 + lk * 2 + 1) ^ (xrow & 7);
            float4 a = *(const float4*)&Xs[xrow * 128 + g0 * 4];
            float4 b = *(const float4*)&Xs[xrow * 128 + g1 * 4];
            u32x4 um, uq;
            um[0] = cvt_pk_bf16(a.x, a.y);
            um[1] = cvt_pk_bf16(a.z, a.w);
            um[2] = cvt_pk_bf16(b.x, b.y);
            um[3] = cvt_pk_bf16(b.z, b.w);
            uq[0] = cvt_pk_bf16(a.x * a.x, a.y * a.y);
            uq[1] = cvt_pk_bf16(a.z * a.z, a.w * a.w);
            uq[2] = cvt_pk_bf16(b.x * b.x, b.y * b.y);
            uq[3] = cvt_pk_bf16(b.z * b.z, b.w * b.w);
            bf16x8 xb = __builtin_bit_cast(bf16x8, um);
            bf16x8 xq = __builtin_bit_cast(bf16x8, uq);
            #pragma unroll
            for (int ntl = 0; ntl < 2; ++ntl) {
                accm[ntl][rt] = __builtin_amdgcn_mfma_f32_16x16x32_bf16(amu[ntl], xb, accm[ntl][rt], 0, 0, 0);
                accv[ntl][rt] = __builtin_amdgcn_mfma_f32_16x16x32_bf16(avr[ntl], xq, accv[ntl][rt], 0, 0, 0);
            }
        }
    }

    __syncthreads();   // all Xs reads done before slabs overwrite the region

    // RF-ReLU epilogue -> b64 LDS writes (XOR-swizzled, 16B granule)
    const float SCALE  = 0.08838834764831845f;  // sqrt(2/256)
    const float SCALE2 = 0.0078125f;            // 2/256
    #pragma unroll
    for (int ntl = 0; ntl < 2; ++ntl) {
        int rf0 = (w * 2 + ntl) * 16 + lk * 4;
        #pragma unroll
        for (int rt = 0; rt < 4; ++rt) {
            int xrow = rt * 16 + lcol;
            float m1[4], v1[4];
            #pragma unroll
            for (int i = 0; i < 4; ++i) {
                float om = accm[ntl][rt][i];
                float ov = accv[ntl][rt][i];
                bool pos = om > 0.f;
                m1[i] = pos ? SCALE  * om : 0.f;
                v1[i] = pos ? SCALE2 * ov : 0.f;
            }
            uint2 pm, pv;
            pm.x = cvt_pk_bf16(m1[0], m1[1]); pm.y = cvt_pk_bf16(m1[2], m1[3]);
            pv.x = cvt_pk_bf16(v1[0], v1[1]); pv.y = cvt_pk_bf16(v1[2], v1[3]);
            int idx = xrow * 256 + (rf0 ^ ((xrow & 7) << 3));
            *(uint2*)&M1s[idx] = pm;
            *(uint2*)&V1s[idx] = pv;
        }
    }

    __syncthreads();

    // ---------------- Layer 2: wave = (d1-tile, ks-half) --------------------
    const int d = w & 3;        // d1-tile (16 cols)
    const int h = w >> 2;       // ks-half: ks in [h*4, h*4+4)
    f32x4 m2a[4], v2a[4];       // [rt] partial sums over this ks-half
    #pragma unroll
    for (int rt = 0; rt < 4; ++rt) { m2a[rt] = (f32x4)0.f; v2a[rt] = (f32x4)0.f; }

    #pragma unroll
    for (int kk = 0; kk < 4; ++kk) {
        int ks = h * 4 + kk;
        int f  = d * 8 + ks;
        bf16x8 amu = *(const bf16x8*)(ws + WS_W2MU  + (size_t)(f * 64 + lane) * 8);
        bf16x8 ac  = *(const bf16x8*)(ws + WS_W2C   + (size_t)(f * 64 + lane) * 8);
        bf16x8 avr = *(const bf16x8*)(ws + WS_W2VAR + (size_t)(f * 64 + lane) * 8);
        #pragma unroll
        for (int rt = 0; rt < 4; ++rt) {
            int xrow = rt * 16 + lcol;
            int base = xrow * 256 + ((ks * 32 + lk * 8) ^ ((xrow & 7) << 3));
            bf16x8 bm  = *(const bf16x8*)&M1s[base];
            bf16x8 bv  = *(const bf16x8*)&V1s[base];
            bf16x8 bms = sq_bf16x8(bm);
            m2a[rt] = __builtin_amdgcn_mfma_f32_16x16x32_bf16(amu, bm,  m2a[rt], 0, 0, 0);
            v2a[rt] = __builtin_amdgcn_mfma_f32_16x16x32_bf16(ac,  bv,  v2a[rt], 0, 0, 0);
            v2a[rt] = __builtin_amdgcn_mfma_f32_16x16x32_bf16(avr, bms, v2a[rt], 0, 0, 0);
        }
    }

    __syncthreads();   // all slab reads done before transpose reuses region

    // ---------------- Combine ks-half partials via transpose buffer ---------
    float* Vp = (float*)sh;            // [64][TP] raw v2
    float* Mp = Vp + BM * TP;          // [64][TP] raw m2
    if (h == 0) {
        #pragma unroll
        for (int rt = 0; rt < 4; ++rt) {
            int xrow = rt * 16 + lcol;
            int d1   = d * 16 + lk * 4;
            *(f32x4*)&Vp[xrow * TP + d1] = v2a[rt];
            *(f32x4*)&Mp[xrow * TP + d1] = m2a[rt];
        }
    }
    __syncthreads();
    if (h == 1) {
        #pragma unroll
        for (int rt = 0; rt < 4; ++rt) {
            int xrow = rt * 16 + lcol;
            int d1   = d * 16 + lk * 4;
            f32x4 vv = *(const f32x4*)&Vp[xrow * TP + d1];
            f32x4 mm = *(const f32x4*)&Mp[xrow * TP + d1];
            vv += v2a[rt];
            mm += m2a[rt];
            *(f32x4*)&Vp[xrow * TP + d1] = vv;
            *(f32x4*)&Mp[xrow * TP + d1] = mm;
        }
    }
    __syncthreads();

    // ---------------- Row-coalesced atomic scatter --------------------------
    // 8 waves x 8 rows; per instruction: one uniform row, 64 consecutive floats
    #pragma unroll
    for (int r = 0; r < 8; ++r) {
        int row = w * 8 + r;
        int g   = __builtin_amdgcn_readfirstlane(Xidx[row0 + row]);
        float vv = Vp[row * TP + lane];
        float mm = Mp[row * TP + lane];
        float p  = 1.0f / (vv + EPSF);
        atomicAdd(accP + (size_t)g * D1 + lane, p);
        atomicAdd(accM + (size_t)g * D1 + lane, p * mm);
    }
}

__global__ void dgp_finalize(float* __restrict__ accM,
                             float* __restrict__ accP, int total)
{
    int idx = blockIdx.x * blockDim.x + threadIdx.x;
    if (idx < total) {
        float var = 1.0f / (accP[idx] + EPSF);   // p_sum = seg_sum + EPS
        accP[idx] = var;                         // embedd_vars
        accM[idx] = accM[idx] * var;             // embedd_means
    }
}

extern "C" void kernel_launch(void* const* d_in, const int* in_sizes, int n_in,
                              void* d_out, int out_size, void* d_ws, size_t ws_size,
                              hipStream_t stream)
{
    const float* X     = (const float*)d_in[0];
    const int*   Xidx  = (const int*)d_in[1];
    const float* W1mu  = (const float*)d_in[2];
    const float* W1var = (const float*)d_in[3];
    const float* W2mu  = (const float*)d_in[4];
    const float* W2var = (const float*)d_in[5];

    const int N = in_sizes[0] / D0;            // 262144
    const int U = out_size / (2 * D1);         // 50000
    float* out  = (float*)d_out;
    float* accM = out;                          // means region
    float* accP = out + (size_t)U * D1;         // vars region
    ushort* ws  = (ushort*)d_ws;

    // harness does not re-poison between replays: re-zero accumulators
    hipMemsetAsync(d_out, 0, (size_t)out_size * sizeof(float), stream);

    convert_w<<<56, 256, 0, stream>>>(W1mu, W1var, W2mu, W2var, ws);

    dgp_mfma<<<N / BM, NT, 0, stream>>>(X, Xidx, ws, accM, accP);

    const int total = U * D1;
    dgp_finalize<<<(total + 255) / 256, 256, 0, stream>>>(accM, accP, total);
}

// Round 11
// 159.076 us; speedup vs baseline: 1.2660x; 1.0654x over previous
//
#include <hip/hip_runtime.h>

#define EPSF 1e-8f

constexpr int D0 = 128;   // input dim
constexpr int R  = 256;   // random features
constexpr int D1 = 64;    // output dim
constexpr int BM = 64;    // rows per block
constexpr int NT = 512;   // threads per block (8 waves)
constexpr int TP = 68;    // transpose buffer stride (f32)

typedef __attribute__((ext_vector_type(8))) short  bf16x8;
typedef __attribute__((ext_vector_type(4))) float  f32x4;
typedef __attribute__((ext_vector_type(4))) uint   u32x4;

// ws layout (ushort elements): bf16 weights in MFMA fragment order
constexpr int WS_W1VAR = 32768;
constexpr int WS_W2MU  = 65536;
constexpr int WS_W2C   = 81920;
constexpr int WS_W2VAR = 98304;

__device__ __forceinline__ ushort f2bf(float x) {
    uint32_t u = __builtin_bit_cast(uint32_t, x);
    u += 0x7FFFu + ((u >> 16) & 1u);          // round-to-nearest-even
    return (ushort)(u >> 16);
}

__device__ __forceinline__ uint cvt_pk_bf16(float lo, float hi) {
    uint r;
    asm("v_cvt_pk_bf16_f32 %0, %1, %2" : "=v"(r) : "v"(lo), "v"(hi));
    return r;
}

// fast reciprocal (v_rcp_f32, ~1e-5 rel err; tolerance is ~2% of max)
__device__ __forceinline__ float fastrcp(float x) {
    return __builtin_amdgcn_rcpf(x);
}

// elementwise square of a bf16x8 fragment
__device__ __forceinline__ bf16x8 sq_bf16x8(bf16x8 a) {
    u32x4 u = __builtin_bit_cast(u32x4, a);
    u32x4 r;
    #pragma unroll
    for (int i = 0; i < 4; ++i) {
        float lo = __builtin_bit_cast(float, u[i] << 16);
        float hi = __builtin_bit_cast(float, u[i] & 0xFFFF0000u);
        r[i] = cvt_pk_bf16(lo * lo, hi * hi);
    }
    return __builtin_bit_cast(bf16x8, r);
}

// --- pre-kernel: convert weights to frag order + zero the output accums ----
__global__ void convert_w(const float* __restrict__ W1mu,
                          const float* __restrict__ W1var,
                          const float* __restrict__ W2mu,
                          const float* __restrict__ W2var,
                          ushort* __restrict__ ws,
                          float4* __restrict__ out4, int total4)
{
    int tid = blockIdx.x * 256 + threadIdx.x;
    if (tid < 8192) {                       // layer 1: 2 mats * 64 frags * 64 lanes
        int m    = tid >> 12;               // 0=mu 1=var
        int f    = (tid >> 6) & 63;         // frag = nt*4 + ks
        int lane = tid & 63;
        int nt = f >> 2, ks = f & 3;
        int col = nt * 16 + (lane & 15);    // rf index (W1 row)
        int k0  = ks * 32 + (lane >> 4) * 8;
        const float* src = (m ? W1var : W1mu) + (size_t)col * D0 + k0;
        ushort* dst = ws + (m ? WS_W1VAR : 0) + (size_t)(f * 64 + lane) * 8;
        #pragma unroll
        for (int j = 0; j < 8; ++j) dst[j] = f2bf(src[j]);
    } else if (tid < 8192 + 3 * 2048) {     // layer 2: 3 mats * 32 frags * 64 lanes
        int t2   = tid - 8192;
        int m    = t2 >> 11;                // 0=mu 1=c 2=var
        int f    = (t2 >> 6) & 31;          // frag = nt*8 + ks
        int lane = t2 & 63;
        int nt = f >> 3, ks = f & 7;
        int col = nt * 16 + (lane & 15);    // d1 index (W2 row)
        int k0  = ks * 32 + (lane >> 4) * 8;
        const float* smu = W2mu  + (size_t)col * R + k0;
        const float* svr = W2var + (size_t)col * R + k0;
        ushort* dst = ws + WS_W2MU + m * 16384 + (size_t)(f * 64 + lane) * 8;
        #pragma unroll
        for (int j = 0; j < 8; ++j) {
            float v;
            if (m == 0)      v = smu[j];
            else if (m == 1) v = fmaf(smu[j], smu[j], svr[j]);  // var + mu^2
            else             v = svr[j];
            dst[j] = f2bf(v);
        }
    }
    // zero the output accumulators (replaces hipMemsetAsync; harness does not
    // re-poison between replays, so this must run every call)
    float4 z = {0.f, 0.f, 0.f, 0.f};
    int nth = gridDim.x * 256;
    for (int i = tid; i < total4; i += nth) out4[i] = z;
}

// --- fused main kernel ------------------------------------------------------
// BM=64, 8 waves, 64 KB LDS (2 blocks/CU).
//  - X staged ONCE as pre-converted bf16 slabs XB (=x) and XQ (=x^2), granule-
//    XOR-swizzled: kills the 8x-redundant per-wave f32->bf16 conversion VALU
//  - layer 1: wave owns 2 rf-tiles x all 4 row-tiles (disjoint weight frags)
//  - layer 2: wave = (d1-tile, ks-half) (disjoint weight frags); partials
//    combined through the LDS transpose buffer
__global__ __launch_bounds__(NT, 4)
void dgp_mfma(const float* __restrict__ X,
              const int*   __restrict__ Xidx,
              const ushort* __restrict__ ws,
              float* __restrict__ accM,
              float* __restrict__ accP)
{
    // 64 KB, phase-aliased:
    //  A: ushort XB[64][128], XQ[64][128]   (16+16 KB, first half of sh)
    //  B: ushort M1s/V1s[64][256]           (32+32 KB)
    //  C: float  Vp/Mp[64][68]              (17.4+17.4 KB)
    __shared__ __align__(16) ushort sh[2 * BM * R];
    ushort* M1s = sh;
    ushort* V1s = sh + BM * R;

    const int t    = threadIdx.x;
    const int lane = t & 63;
    const int w    = t >> 6;         // wave 0..7
    const int row0 = blockIdx.x * BM;
    const int lcol = lane & 15;      // X-row within 16-tile
    const int lk   = lane >> 4;      // 0..3

    // ---------------- Stage X as converted bf16 slabs (once) ----------------
    {
        ushort* XB = sh;             // [64][128] bf16, granule-XOR swizzle
        ushort* XQ = sh + 8192;
        int row = t >> 3;            // 0..63
        int cb  = t & 7;             // 16-float chunk = 2 granules
        const float4* src = (const float4*)(X + (size_t)(row0 + row) * D0) + cb * 4;
        float4 a0 = src[0], a1 = src[1], a2 = src[2], a3 = src[3];
        u32x4 b0, b1, q0, q1;
        b0[0] = cvt_pk_bf16(a0.x, a0.y); b0[1] = cvt_pk_bf16(a0.z, a0.w);
        b0[2] = cvt_pk_bf16(a1.x, a1.y); b0[3] = cvt_pk_bf16(a1.z, a1.w);
        b1[0] = cvt_pk_bf16(a2.x, a2.y); b1[1] = cvt_pk_bf16(a2.z, a2.w);
        b1[2] = cvt_pk_bf16(a3.x, a3.y); b1[3] = cvt_pk_bf16(a3.z, a3.w);
        q0[0] = cvt_pk_bf16(a0.x * a0.x, a0.y * a0.y);
        q0[1] = cvt_pk_bf16(a0.z * a0.z, a0.w * a0.w);
        q0[2] = cvt_pk_bf16(a1.x * a1.x, a1.y * a1.y);
        q0[3] = cvt_pk_bf16(a1.z * a1.z, a1.w * a1.w);
        q1[0] = cvt_pk_bf16(a2.x * a2.x, a2.y * a2.y);
        q1[1] = cvt_pk_bf16(a2.z * a2.z, a2.w * a2.w);
        q1[2] = cvt_pk_bf16(a3.x * a3.x, a3.y * a3.y);
        q1[3] = cvt_pk_bf16(a3.z * a3.z, a3.w * a3.w);
        int gs0 = (cb * 2) ^ (row & 7);
        int gs1 = (cb * 2 + 1) ^ (row & 7);
        *(u32x4*)&XB[row * 128 + gs0 * 8] = b0;
        *(u32x4*)&XB[row * 128 + gs1 * 8] = b1;
        *(u32x4*)&XQ[row * 128 + gs0 * 8] = q0;
        *(u32x4*)&XQ[row * 128 + gs1 * 8] = q1;
    }
    __syncthreads();

    // ---------------- Layer 1: W1·X^T (mu) and W1var·(X^2)^T ----------------
    // wave w owns rf-tiles {2w, 2w+1}, all 4 row-tiles
    const ushort* XB = sh;
    const ushort* XQ = sh + 8192;
    f32x4 accm[2][4], accv[2][4];   // [ntl][rt]
    #pragma unroll
    for (int ntl = 0; ntl < 2; ++ntl)
        #pragma unroll
        for (int rt = 0; rt < 4; ++rt) {
            accm[ntl][rt] = (f32x4)0.f;
            accv[ntl][rt] = (f32x4)0.f;
        }

    #pragma unroll
    for (int ks = 0; ks < 4; ++ks) {
        bf16x8 amu[2], avr[2];
        #pragma unroll
        for (int ntl = 0; ntl < 2; ++ntl) {
            int f = (w * 2 + ntl) * 4 + ks;
            amu[ntl] = *(const bf16x8*)(ws + (size_t)(f * 64 + lane) * 8);
            avr[ntl] = *(const bf16x8*)(ws + WS_W1VAR + (size_t)(f * 64 + lane) * 8);
        }
        #pragma unroll
        for (int rt = 0; rt < 4; ++rt) {
            int xrow = rt * 16 + lcol;
            int gidx = (ks * 4 + lk) ^ (xrow & 7);
            bf16x8 xb = *(const bf16x8*)&XB[xrow * 128 + gidx * 8];
            bf16x8 xq = *(const bf16x8*)&XQ[xrow * 128 + gidx * 8];
            #pragma unroll
            for (int ntl = 0; ntl < 2; ++ntl) {
                accm[ntl][rt] = __builtin_amdgcn_mfma_f32_16x16x32_bf16(amu[ntl], xb, accm[ntl][rt], 0, 0, 0);
                accv[ntl][rt] = __builtin_amdgcn_mfma_f32_16x16x32_bf16(avr[ntl], xq, accv[ntl][rt], 0, 0, 0);
            }
        }
    }

    __syncthreads();   // all XB/XQ reads done before slabs overwrite region

    // RF-ReLU epilogue -> b64 LDS writes (XOR-swizzled, 16B granule)
    const float SCALE  = 0.08838834764831845f;  // sqrt(2/256)
    const float SCALE2 = 0.0078125f;            // 2/256
    #pragma unroll
    for (int ntl = 0; ntl < 2; ++ntl) {
        int rf0 = (w * 2 + ntl) * 16 + lk * 4;
        #pragma unroll
        for (int rt = 0; rt < 4; ++rt) {
            int xrow = rt * 16 + lcol;
            float m1[4], v1[4];
            #pragma unroll
            for (int i = 0; i < 4; ++i) {
                float om = accm[ntl][rt][i];
                float ov = accv[ntl][rt][i];
                bool pos = om > 0.f;
                m1[i] = pos ? SCALE  * om : 0.f;
                v1[i] = pos ? SCALE2 * ov : 0.f;
            }
            uint2 pm, pv;
            pm.x = cvt_pk_bf16(m1[0], m1[1]); pm.y = cvt_pk_bf16(m1[2], m1[3]);
            pv.x = cvt_pk_bf16(v1[0], v1[1]); pv.y = cvt_pk_bf16(v1[2], v1[3]);
            int idx = xrow * 256 + (rf0 ^ ((xrow & 7) << 3));
            *(uint2*)&M1s[idx] = pm;
            *(uint2*)&V1s[idx] = pv;
        }
    }

    __syncthreads();

    // ---------------- Layer 2: wave = (d1-tile, ks-half) --------------------
    const int d = w & 3;        // d1-tile (16 cols)
    const int h = w >> 2;       // ks-half: ks in [h*4, h*4+4)
    f32x4 m2a[4], v2a[4];       // [rt] partial sums over this ks-half
    #pragma unroll
    for (int rt = 0; rt < 4; ++rt) { m2a[rt] = (f32x4)0.f; v2a[rt] = (f32x4)0.f; }

    #pragma unroll
    for (int kk = 0; kk < 4; ++kk) {
        int ks = h * 4 + kk;
        int f  = d * 8 + ks;
        bf16x8 amu = *(const bf16x8*)(ws + WS_W2MU  + (size_t)(f * 64 + lane) * 8);
        bf16x8 ac  = *(const bf16x8*)(ws + WS_W2C   + (size_t)(f * 64 + lane) * 8);
        bf16x8 avr = *(const bf16x8*)(ws + WS_W2VAR + (size_t)(f * 64 + lane) * 8);
        #pragma unroll
        for (int rt = 0; rt < 4; ++rt) {
            int xrow = rt * 16 + lcol;
            int base = xrow * 256 + ((ks * 32 + lk * 8) ^ ((xrow & 7) << 3));
            bf16x8 bm  = *(const bf16x8*)&M1s[base];
            bf16x8 bv  = *(const bf16x8*)&V1s[base];
            bf16x8 bms = sq_bf16x8(bm);
            m2a[rt] = __builtin_amdgcn_mfma_f32_16x16x32_bf16(amu, bm,  m2a[rt], 0, 0, 0);
            v2a[rt] = __builtin_amdgcn_mfma_f32_16x16x32_bf16(ac,  bv,  v2a[rt], 0, 0, 0);
            v2a[rt] = __builtin_amdgcn_mfma_f32_16x16x32_bf16(avr, bms, v2a[rt], 0, 0, 0);
        }
    }

    __syncthreads();   // all slab reads done before transpose reuses region

    // ---------------- Combine ks-half partials via transpose buffer ---------
    float* Vp = (float*)sh;            // [64][TP] raw v2
    float* Mp = Vp + BM * TP;          // [64][TP] raw m2
    if (h == 0) {
        #pragma unroll
        for (int rt = 0; rt < 4; ++rt) {
            int xrow = rt * 16 + lcol;
            int d1   = d * 16 + lk * 4;
            *(f32x4*)&Vp[xrow * TP + d1] = v2a[rt];
            *(f32x4*)&Mp[xrow * TP + d1] = m2a[rt];
        }
    }
    __syncthreads();
    if (h == 1) {
        #pragma unroll
        for (int rt = 0; rt < 4; ++rt) {
            int xrow = rt * 16 + lcol;
            int d1   = d * 16 + lk * 4;
            f32x4 vv = *(const f32x4*)&Vp[xrow * TP + d1];
            f32x4 mm = *(const f32x4*)&Mp[xrow * TP + d1];
            vv += v2a[rt];
            mm += m2a[rt];
            *(f32x4*)&Vp[xrow * TP + d1] = vv;
            *(f32x4*)&Mp[xrow * TP + d1] = mm;
        }
    }
    __syncthreads();

    // ---------------- Row-coalesced atomic scatter --------------------------
    // 8 waves x 8 rows; per instruction: one uniform row, 64 consecutive floats
    #pragma unroll
    for (int r = 0; r < 8; ++r) {
        int row = w * 8 + r;
        int g   = __builtin_amdgcn_readfirstlane(Xidx[row0 + row]);
        float vv = Vp[row * TP + lane];
        float mm = Mp[row * TP + lane];
        float p  = fastrcp(vv + EPSF);
        atomicAdd(accP + (size_t)g * D1 + lane, p);
        atomicAdd(accM + (size_t)g * D1 + lane, p * mm);
    }
}

__global__ void dgp_finalize(float4* __restrict__ accM4,
                             float4* __restrict__ accP4, int total4)
{
    int idx = blockIdx.x * blockDim.x + threadIdx.x;
    if (idx < total4) {
        float4 pv = accP4[idx];
        float4 var;
        var.x = fastrcp(pv.x + EPSF);
        var.y = fastrcp(pv.y + EPSF);
        var.z = fastrcp(pv.z + EPSF);
        var.w = fastrcp(pv.w + EPSF);
        accP4[idx] = var;                        // embedd_vars
        float4 mv = accM4[idx];
        mv.x *= var.x; mv.y *= var.y; mv.z *= var.z; mv.w *= var.w;
        accM4[idx] = mv;                         // embedd_means
    }
}

extern "C" void kernel_launch(void* const* d_in, const int* in_sizes, int n_in,
                              void* d_out, int out_size, void* d_ws, size_t ws_size,
                              hipStream_t stream)
{
    const float* X     = (const float*)d_in[0];
    const int*   Xidx  = (const int*)d_in[1];
    const float* W1mu  = (const float*)d_in[2];
    const float* W1var = (const float*)d_in[3];
    const float* W2mu  = (const float*)d_in[4];
    const float* W2var = (const float*)d_in[5];

    const int N = in_sizes[0] / D0;            // 262144
    const int U = out_size / (2 * D1);         // 50000
    float* out  = (float*)d_out;
    float* accM = out;                          // means region
    float* accP = out + (size_t)U * D1;         // vars region
    ushort* ws  = (ushort*)d_ws;
    const int total4 = out_size / 4;           // float4 count (out_size = 2*U*64)

    // convert weights AND zero the accumulators (memset folded in)
    convert_w<<<2048, 256, 0, stream>>>(W1mu, W1var, W2mu, W2var, ws,
                                        (float4*)d_out, total4);

    dgp_mfma<<<N / BM, NT, 0, stream>>>(X, Xidx, ws, accM, accP);

    const int fin4 = (U * D1) / 4;             // per-array float4 count
    dgp_finalize<<<(fin4 + 255) / 256, 256, 0, stream>>>(
        (float4*)accM, (float4*)accP, fin4);
}